// Round 13
// baseline (900.892 us; speedup 1.0000x reference)
//
#include <hip/hip_runtime.h>
#include <hip/hip_bf16.h>
#include <math.h>

#define B_ 16
#define N_ 2048
#define KNN 20
#define SLOPE 0.2f
#define EPS_ 1e-5f

#define SEG 8
#define SEGLEN (N_ / SEG)   // 256
#define QPB 64              // queries per block (2 per thread)
#define CAP 64              // collected-candidate capacity per query

typedef __attribute__((ext_vector_type(8))) short short8;
typedef __attribute__((ext_vector_type(4))) float float4v;

// ------------------------------------------- kNN + EdgeConv (fused)
// scan1 samples HALF the candidates (4 of 8 chunks/segment) -- still 24
// actual-distance samples => threshold stays conservative; overflow
// fallback (exact rescan) keeps correctness. After the top-20 ladder the
// block computes EdgeConv for its own 64 queries from pts4 + stashed idx
// (identical FMA order to the old edge_kernel => bitwise-same cat/stats).
__global__ __launch_bounds__(256, 2) void knn_kernel(const float* __restrict__ x,
                                                     int* __restrict__ idx,
                                                     const float* __restrict__ w_edge,
                                                     const float* __restrict__ b_edge,
                                                     float* __restrict__ cat,
                                                     double* __restrict__ stats) {
    __shared__ float4 pts4[N_];          // 32 KB: x,y,z,|p|^2
    __shared__ union {
        float thr[QPB * 24];             // scan-1 samples (dead after threshold)
        int sidx[QPB * KNN];             // stashed neighbor idx (ladder -> edge)
    } u2;
    __shared__ float tq[QPB];
    __shared__ int cnt[QPB];
    __shared__ float lv[QPB * CAP];      // 16 KB
    __shared__ int   li[QPB * CAP];      // 16 KB
    __shared__ float ws[64 * 6];
    __shared__ float bs[64];
    __shared__ float s_sum[64], s_sq[64];

    const int b = blockIdx.x >> 5;       // 32 blocks per batch
    const int qb = blockIdx.x & 31;
    const float* xb = x + (size_t)b * N_ * 3;
    for (int i = threadIdx.x; i < N_; i += 256) {
        float xv = xb[i * 3], yv = xb[i * 3 + 1], zv = xb[i * 3 + 2];
        pts4[i] = make_float4(xv, yv, zv, xv * xv + yv * yv + zv * zv);
    }
    for (int i = threadIdx.x; i < 64 * 6; i += 256) ws[i] = w_edge[i];
    if (threadIdx.x < QPB) {
        cnt[threadIdx.x] = 0;
        bs[threadIdx.x] = b_edge[threadIdx.x];
        s_sum[threadIdx.x] = 0.f; s_sq[threadIdx.x] = 0.f;
    }
    __syncthreads();

    const int s = threadIdx.x >> 5;      // segment 0..7 (uniform per half-wave)
    const int qs = threadIdx.x & 31;     // query-pair slot
    const int q0 = qs * 2, q1 = q0 + 1;
    const int n0 = qb * QPB + q0;
    const float4 pa = pts4[n0];
    const float4 pb = pts4[n0 + 1];
    const int m0 = s * SEGLEN;

    // ---- scan 1: 4 chunk-maxes of 32 (HALF-sampled), 8-deep load batching
    float ca[4], cb[4];
#pragma unroll
    for (int c = 0; c < 4; ++c) {
        float va0 = -INFINITY, va1 = -INFINITY;
        float vb0 = -INFINITY, vb1 = -INFINITY;
        for (int g = 0; g < 4; ++g) {
            float4 r[8];
#pragma unroll
            for (int j = 0; j < 8; ++j) r[j] = pts4[m0 + c * 64 + g * 8 + j];
#pragma unroll
            for (int j = 0; j < 8; ++j) {
                const float da = 2.f * (pa.x * r[j].x + pa.y * r[j].y + pa.z * r[j].z)
                                 - pa.w - r[j].w;
                const float db = 2.f * (pb.x * r[j].x + pb.y * r[j].y + pb.z * r[j].z)
                                 - pb.w - r[j].w;
                if (j & 1) { va1 = fmaxf(va1, da); vb1 = fmaxf(vb1, db); }
                else       { va0 = fmaxf(va0, da); vb0 = fmaxf(vb0, db); }
            }
        }
        ca[c] = fmaxf(va0, va1); cb[c] = fmaxf(vb0, vb1);
    }
    // top-3 of the 4 chunk maxes per query (branch-free carried min/max)
    {
        float t0 = -INFINITY, t1 = -INFINITY, t2 = -INFINITY;
        float u0 = -INFINITY, u1 = -INFINITY, u2v = -INFINITY;
#pragma unroll
        for (int c = 0; c < 4; ++c) {
            float v = ca[c];
            float r0 = fminf(t0, v); t0 = fmaxf(t0, v);
            float r1 = fminf(t1, r0); t1 = fmaxf(t1, r0);
            t2 = fmaxf(t2, r1);
            float w = cb[c];
            float s0 = fminf(u0, w); u0 = fmaxf(u0, w);
            float s1 = fminf(u1, s0); u1 = fmaxf(u1, s0);
            u2v = fmaxf(u2v, s1);
        }
        u2.thr[q0 * 24 + s * 3 + 0] = t0;
        u2.thr[q0 * 24 + s * 3 + 1] = t1;
        u2.thr[q0 * 24 + s * 3 + 2] = t2;
        u2.thr[q1 * 24 + s * 3 + 0] = u0;
        u2.thr[q1 * 24 + s * 3 + 1] = u1;
        u2.thr[q1 * 24 + s * 3 + 2] = u2v;
    }
    __syncthreads();

    // ---- threshold: 20th largest of 24 = 5th smallest; conservative epsilon
    if (threadIdx.x < QPB) {
        const int qq = threadIdx.x;
        float s0 = INFINITY, s1 = INFINITY, s2 = INFINITY, s3 = INFINITY, s4 = INFINITY;
#pragma unroll
        for (int j = 0; j < 24; ++j) {
            float c = u2.thr[qq * 24 + j];
            float u;
            u = fminf(s0, c); c = fmaxf(s0, c); s0 = u;
            u = fminf(s1, c); c = fmaxf(s1, c); s1 = u;
            u = fminf(s2, c); c = fmaxf(s2, c); s2 = u;
            u = fminf(s3, c); c = fmaxf(s3, c); s3 = u;
            s4 = fminf(s4, c);
        }
        tq[qq] = s4 - (fabsf(s4) * 1e-6f + 1e-6f);
    }
    __syncthreads();

    // ---- scan 2: collect candidates >= t for both queries (8-deep batches)
    const float ta = tq[q0];
    const float tb = tq[q1];
    for (int g = 0; g < 32; ++g) {
        float4 r[8];
#pragma unroll
        for (int j = 0; j < 8; ++j) r[j] = pts4[m0 + g * 8 + j];
#pragma unroll
        for (int j = 0; j < 8; ++j) {
            const int m = m0 + g * 8 + j;
            const float da = 2.f * (pa.x * r[j].x + pa.y * r[j].y + pa.z * r[j].z)
                             - pa.w - r[j].w;
            const float db = 2.f * (pb.x * r[j].x + pb.y * r[j].y + pb.z * r[j].z)
                             - pb.w - r[j].w;
            if (da >= ta) {
                int pos = atomicAdd(&cnt[q0], 1);
                if (pos < CAP) { lv[q0 * CAP + pos] = da; li[q0 * CAP + pos] = m; }
            }
            if (db >= tb) {
                int pos = atomicAdd(&cnt[q1], 1);
                if (pos < CAP) { lv[q1 * CAP + pos] = db; li[q1 * CAP + pos] = m; }
            }
        }
    }
    __syncthreads();   // also: thr is dead from here; sidx overlay becomes safe

    // ---- exact top-20 per query, stash idx for edge phase
    if (threadIdx.x < QPB) {
        const int qq = threadIdx.x;
        const int nn = qb * QPB + qq;
        int* op = idx + (size_t)(b * N_ + nn) * KNN;
        float vals[KNN]; int inds[KNN];
#pragma unroll
        for (int j = 0; j < KNN; ++j) { vals[j] = -INFINITY; inds[j] = 0; }
        const int c = cnt[qq];
        if (c <= CAP) {
            for (int j = 0; j < c; ++j) {
                const float v = lv[qq * CAP + j];
                if (v > vals[KNN - 1]) {
                    float cv = v; int ci = li[qq * CAP + j];
#pragma unroll
                    for (int k = 0; k < KNN; ++k) {
                        const bool sw = cv > vals[k];
                        const float tv = vals[k]; const int ti = inds[k];
                        vals[k] = sw ? cv : tv;  inds[k] = sw ? ci : ti;
                        cv      = sw ? tv : cv;  ci      = sw ? ti : ci;
                    }
                }
            }
        } else {
            // overflow fallback: exact full rescan (rare)
            const float4 pq2 = pts4[nn];
            for (int m = 0; m < N_; ++m) {
                const float4 p = pts4[m];
                const float d = 2.f * (pq2.x * p.x + pq2.y * p.y + pq2.z * p.z)
                                - pq2.w - p.w;
                if (d > vals[KNN - 1]) {
                    float cv = d; int ci = m;
#pragma unroll
                    for (int k = 0; k < KNN; ++k) {
                        const bool sw = cv > vals[k];
                        const float tv = vals[k]; const int ti = inds[k];
                        vals[k] = sw ? cv : tv;  inds[k] = sw ? ci : ti;
                        cv      = sw ? tv : cv;  ci      = sw ? ti : ci;
                    }
                }
            }
        }
#pragma unroll
        for (int j = 0; j < KNN; ++j) {
            op[j] = inds[j];
            u2.sidx[qq * KNN + j] = inds[j];
        }
    }
    __syncthreads();

    // ---- EdgeConv phase (identical arithmetic to the old edge_kernel)
    {
        const int p = threadIdx.x >> 2;     // point 0..63
        const int cg = threadIdx.x & 3;     // channel group (16 ch)
        const int n = qb * QPB + p;
        const float4 ctr = pts4[n];
        const float cx = ctr.x, cy = ctr.y, cz = ctr.z;

        float maxv[16], sum[16], sq[16];
#pragma unroll
        for (int i = 0; i < 16; ++i) { maxv[i] = -INFINITY; sum[i] = 0.f; sq[i] = 0.f; }

        for (int k = 0; k < KNN; ++k) {
            const int j = u2.sidx[p * KNN + k];
            const float4 nb = pts4[j];
            const float dx = nb.x - cx, dy = nb.y - cy, dz = nb.z - cz;
#pragma unroll
            for (int i = 0; i < 16; ++i) {
                const int o = cg * 16 + i;
                const float* wr = &ws[o * 6];
                float h = bs[o] + wr[0] * dx + wr[1] * dy + wr[2] * dz
                                + wr[3] * cx + wr[4] * cy + wr[5] * cz;
                sum[i] += h; sq[i] += h * h;
                maxv[i] = fmaxf(maxv[i], h);
            }
        }

        float* cp = cat + (size_t)(b * N_ + n) * 512 + cg * 16;
#pragma unroll
        for (int i4 = 0; i4 < 4; ++i4)
            *(float4*)&cp[i4 * 4] = make_float4(maxv[i4 * 4], maxv[i4 * 4 + 1],
                                                maxv[i4 * 4 + 2], maxv[i4 * 4 + 3]);
        float ls = 0.f, lq = 0.f;   // per-thread partial over its 16 channels? no:
#pragma unroll
        for (int i = 0; i < 16; ++i) {
            atomicAdd(&s_sum[cg * 16 + i], sum[i]);
            atomicAdd(&s_sq[cg * 16 + i], sq[i]);
        }
        (void)ls; (void)lq;
    }
    __syncthreads();
    if (threadIdx.x < 64) {
        atomicAdd(&stats[threadIdx.x], (double)s_sum[threadIdx.x]);
        atomicAdd(&stats[64 + threadIdx.x], (double)s_sq[threadIdx.x]);
    }
}

// ----------------------------------------------------- w_final -> bf16
__global__ __launch_bounds__(256) void wconv_kernel(const float* __restrict__ w,
                                                    __hip_bfloat16* __restrict__ wb) {
    int t = blockIdx.x * 256 + threadIdx.x;   // 1024*512
    wb[t] = __float2bfloat16(w[t]);
}

// -------------------- graph max-pool + input-BN+LReLU + 1x1 conv + stats
// XCD-swizzled block decode: batch = blockIdx & 15 (all 32 blocks of a batch
// share one XCD with round-robin mapping -> neighbor slab stays L2-resident).
template <int CIN, int COUT, int PT>
__global__ __launch_bounds__(256) void layer_kernel(float* __restrict__ cat,
                                                    const int* __restrict__ idx,
                                                    const float* __restrict__ w,
                                                    const float* __restrict__ bias,
                                                    const double* __restrict__ stats_in,
                                                    double invcnt_in,
                                                    double* __restrict__ stats_out,
                                                    int off_in, int off_out) {
    constexpr int P = 64;
    constexpr int LDC = CIN + 4;        // g row stride, 16B-aligned
    constexpr int WS = COUT + 4;        // wt row stride
    constexpr int NCG = CIN / 4;        // channel float4 groups
    constexpr int PPAR = 256 / NCG;     // points gathered in parallel
    constexpr int NOG = COUT / 4;       // output quad groups
    static_assert(NOG * (P / PT) == 256, "thread mapping");

    __shared__ float g[P * LDC];
    __shared__ float wt[16 * WS];       // [cc][o] — lane-contiguous, conflict-free
    __shared__ float s_sum[COUT], s_sq[COUT];

    const int b = blockIdx.x & 15;      // XCD swizzle: batch fast-varying
    const int pb = blockIdx.x >> 4;     // 0..31
    const int pt0 = b * N_ + pb * P;    // flattened b*N+n

    // ---- gather + max + input BN/LReLU
    {
        const int cg = threadIdx.x % NCG;
        const int pp = threadIdx.x / NCG;
        float mean[4], inv[4];
#pragma unroll
        for (int j = 0; j < 4; ++j) {
            const double mu = stats_in[cg * 4 + j] * invcnt_in;
            const double e2 = stats_in[CIN + cg * 4 + j] * invcnt_in;
            const float var = (float)(e2 - mu * mu);
            mean[j] = (float)mu;
            inv[j] = rsqrtf(var + EPS_);
        }
        for (int p = pp; p < P; p += PPAR) {
            const int* ip = idx + (size_t)(pt0 + p) * KNN;
            float4 m = make_float4(-INFINITY, -INFINITY, -INFINITY, -INFINITY);
#pragma unroll
            for (int k = 0; k < KNN; ++k) {
                const int j = ip[k];
                const float4 v = *(const float4*)&cat[(size_t)(b * N_ + j) * 512 + off_in + cg * 4];
                m.x = fmaxf(m.x, v.x); m.y = fmaxf(m.y, v.y);
                m.z = fmaxf(m.z, v.z); m.w = fmaxf(m.w, v.w);
            }
            float4 r;
            r.x = (m.x - mean[0]) * inv[0]; r.x = r.x >= 0.f ? r.x : SLOPE * r.x;
            r.y = (m.y - mean[1]) * inv[1]; r.y = r.y >= 0.f ? r.y : SLOPE * r.y;
            r.z = (m.z - mean[2]) * inv[2]; r.z = r.z >= 0.f ? r.z : SLOPE * r.z;
            r.w = (m.w - mean[3]) * inv[3]; r.w = r.w >= 0.f ? r.w : SLOPE * r.w;
            *(float4*)&g[p * LDC + cg * 4] = r;
        }
    }
    if (threadIdx.x < COUT) { s_sum[threadIdx.x] = 0.f; s_sq[threadIdx.x] = 0.f; }

    // ---- conv: 4 outs x PT points per thread
    const int og = threadIdx.x % NOG;
    const int pg = threadIdx.x / NOG;
    const int o0 = og * 4, p0 = pg * PT;

    float acc[4][PT];
#pragma unroll
    for (int i = 0; i < 4; ++i)
#pragma unroll
        for (int j = 0; j < PT; ++j) acc[i][j] = 0.f;

    for (int c0 = 0; c0 < CIN; c0 += 16) {
        __syncthreads();
        for (int i = threadIdx.x; i < COUT * 16; i += 256) {
            int o = i >> 4, cc = i & 15;
            wt[cc * WS + o] = w[(size_t)o * CIN + c0 + cc];
        }
        __syncthreads();
#pragma unroll
        for (int ccq = 0; ccq < 4; ++ccq) {
            const float4 w0 = *(const float4*)&wt[(ccq * 4 + 0) * WS + o0];
            const float4 w1 = *(const float4*)&wt[(ccq * 4 + 1) * WS + o0];
            const float4 w2 = *(const float4*)&wt[(ccq * 4 + 2) * WS + o0];
            const float4 w3 = *(const float4*)&wt[(ccq * 4 + 3) * WS + o0];
#pragma unroll
            for (int p = 0; p < PT; ++p) {
                const float4 gv = *(const float4*)&g[(p0 + p) * LDC + c0 + ccq * 4];
                acc[0][p] += w0.x * gv.x; acc[0][p] += w1.x * gv.y;
                acc[0][p] += w2.x * gv.z; acc[0][p] += w3.x * gv.w;
                acc[1][p] += w0.y * gv.x; acc[1][p] += w1.y * gv.y;
                acc[1][p] += w2.y * gv.z; acc[1][p] += w3.y * gv.w;
                acc[2][p] += w0.z * gv.x; acc[2][p] += w1.z * gv.y;
                acc[2][p] += w2.z * gv.z; acc[2][p] += w3.z * gv.w;
                acc[3][p] += w0.w * gv.x; acc[3][p] += w1.w * gv.y;
                acc[3][p] += w2.w * gv.z; acc[3][p] += w3.w * gv.w;
            }
        }
    }

    // ---- epilogue: bias, stats, contiguous float4 stores (PRE-BN output)
    const float4 bv = *(const float4*)&bias[o0];
    float lsum[4] = {0.f, 0.f, 0.f, 0.f}, lsq[4] = {0.f, 0.f, 0.f, 0.f};
#pragma unroll
    for (int p = 0; p < PT; ++p) {
        float4 hv;
        hv.x = acc[0][p] + bv.x; hv.y = acc[1][p] + bv.y;
        hv.z = acc[2][p] + bv.z; hv.w = acc[3][p] + bv.w;
        lsum[0] += hv.x; lsq[0] += hv.x * hv.x;
        lsum[1] += hv.y; lsq[1] += hv.y * hv.y;
        lsum[2] += hv.z; lsq[2] += hv.z * hv.z;
        lsum[3] += hv.w; lsq[3] += hv.w * hv.w;
        *(float4*)&cat[(size_t)(pt0 + p0 + p) * 512 + off_out + o0] = hv;
    }
#pragma unroll
    for (int i = 0; i < 4; ++i) {
        atomicAdd(&s_sum[o0 + i], lsum[i]);
        atomicAdd(&s_sq[o0 + i], lsq[i]);
    }
    __syncthreads();
    if (threadIdx.x < COUT) {
        atomicAdd(&stats_out[threadIdx.x], (double)s_sum[threadIdx.x]);
        atomicAdd(&stats_out[COUT + threadIdx.x], (double)s_sq[threadIdx.x]);
    }
}

// ------------- fused BN+LReLU -> bf16 for all 512 channels (final GEMM input)
__global__ __launch_bounds__(256) void bnconv_kernel(const float* __restrict__ cat,
                                                     const double* __restrict__ stats,
                                                     unsigned short* __restrict__ catb,
                                                     double ik, double in_) {
    const int t = blockIdx.x * 256 + threadIdx.x;   // over 32768*128 float4s
    const int pn = t >> 7;
    const int c = (t & 127) * 4;

    const double* sp; const double* qp; double icnt;
    if (c < 64)       { sp = stats + c;             qp = stats + 64 + c;        icnt = ik; }
    else if (c < 128) { sp = stats + 128 + (c - 64);  qp = stats + 192 + (c - 64);  icnt = in_; }
    else if (c < 256) { sp = stats + 256 + (c - 128); qp = stats + 384 + (c - 128); icnt = in_; }
    else              { sp = stats + 512 + (c - 256); qp = stats + 768 + (c - 256); icnt = in_; }

    const float4 v = *(const float4*)&cat[(size_t)pn * 512 + c];
    float r[4]; const float vv[4] = {v.x, v.y, v.z, v.w};
#pragma unroll
    for (int j = 0; j < 4; ++j) {
        const double mu = sp[j] * icnt;
        const double e2 = qp[j] * icnt;
        const float var = (float)(e2 - mu * mu);
        const float inv = rsqrtf(var + EPS_);
        float x = (vv[j] - (float)mu) * inv;
        r[j] = x >= 0.f ? x : SLOPE * x;
    }
    ushort4 o;
    __hip_bfloat16 h0 = __float2bfloat16(r[0]); o.x = *(unsigned short*)&h0;
    __hip_bfloat16 h1 = __float2bfloat16(r[1]); o.y = *(unsigned short*)&h1;
    __hip_bfloat16 h2 = __float2bfloat16(r[2]); o.z = *(unsigned short*)&h2;
    __hip_bfloat16 h3 = __float2bfloat16(r[3]); o.w = *(unsigned short*)&h3;
    *(ushort4*)&catb[(size_t)pn * 512 + c] = o;
}

// -------------- final GEMM via bf16 MFMA + bias + max-over-n (register staging)
__global__ __launch_bounds__(256) void final_mfma_kernel(const short* __restrict__ catb,
                                                         const short* __restrict__ wb,
                                                         const float* __restrict__ bias,
                                                         float* __restrict__ partial) {
    constexpr int LDK = 72;              // 64 + 8 pad: 144 B row stride (16B-aligned)
    __shared__ short As[128 * LDK];
    __shared__ short Bs[128 * LDK];
    __shared__ float red[256];

    const int ob = blockIdx.x;     // 0..7, fast-varying: A tile stays L2/LLC-hot
    const int pblk = blockIdx.y;   // 0..255
    const int pt0 = pblk * 128;

    const int wid = threadIdx.x >> 6;
    const int lane = threadIdx.x & 63;
    const int wm = wid >> 1, wn = wid & 1;   // 2x2 wave grid -> 64x64 per wave
    const int lm = lane & 15, g = lane >> 4;

    const int srow = threadIdx.x >> 1;
    const int scg = (threadIdx.x & 1) * 32;
    const short* ga = catb + (size_t)(pt0 + srow) * 512 + scg;
    const short* gb = wb + (size_t)(ob * 128 + srow) * 512 + scg;
    short* la = As + srow * LDK + scg;
    short* lb = Bs + srow * LDK + scg;

    float4v acc[4][4];
#pragma unroll
    for (int i = 0; i < 4; ++i)
#pragma unroll
        for (int j = 0; j < 4; ++j) acc[i][j] = {0.f, 0.f, 0.f, 0.f};

    short8 ra[4], rb[4];
#pragma unroll
    for (int j = 0; j < 4; ++j) {
        ra[j] = *(const short8*)(ga + j * 8);
        rb[j] = *(const short8*)(gb + j * 8);
    }

    for (int step = 0; step < 8; ++step) {
        __syncthreads();
#pragma unroll
        for (int j = 0; j < 4; ++j) {
            *(short8*)(la + j * 8) = ra[j];
            *(short8*)(lb + j * 8) = rb[j];
        }
        __syncthreads();
        if (step < 7) {
            const int c1 = (step + 1) * 64;
#pragma unroll
            for (int j = 0; j < 4; ++j) {
                ra[j] = *(const short8*)(ga + c1 + j * 8);
                rb[j] = *(const short8*)(gb + c1 + j * 8);
            }
        }
#pragma unroll
        for (int kk = 0; kk < 2; ++kk) {
            short8 a[4], b[4];
#pragma unroll
            for (int t = 0; t < 4; ++t) {
                a[t] = *(const short8*)&As[(wm * 64 + t * 16 + lm) * LDK + kk * 32 + g * 8];
                b[t] = *(const short8*)&Bs[(wn * 64 + t * 16 + lm) * LDK + kk * 32 + g * 8];
            }
#pragma unroll
            for (int mt = 0; mt < 4; ++mt)
#pragma unroll
                for (int nt = 0; nt < 4; ++nt)
                    acc[mt][nt] = __builtin_amdgcn_mfma_f32_16x16x32_bf16(
                        a[mt], b[nt], acc[mt][nt], 0, 0, 0);
        }
    }

    float cm[4];
#pragma unroll
    for (int nt = 0; nt < 4; ++nt) {
        float m = -INFINITY;
#pragma unroll
        for (int mt = 0; mt < 4; ++mt)
#pragma unroll
            for (int r = 0; r < 4; ++r) m = fmaxf(m, acc[mt][nt][r]);
        m = fmaxf(m, __shfl_xor(m, 16, 64));
        m = fmaxf(m, __shfl_xor(m, 32, 64));
        cm[nt] = m;
    }
    __syncthreads();
    if (lane < 16) {
#pragma unroll
        for (int nt = 0; nt < 4; ++nt)
            red[wm * 128 + wn * 64 + nt * 16 + lane] = cm[nt];
    }
    __syncthreads();
    if (threadIdx.x < 128) {
        const int o = threadIdx.x;
        float v = fmaxf(red[o], red[128 + o]) + bias[ob * 128 + o];
        partial[(size_t)pblk * 1024 + ob * 128 + o] = v;
    }
}

// ----------------------------------------------------------- final reduce
__global__ __launch_bounds__(256) void reduce_kernel(const float* __restrict__ partial,
                                                     float* __restrict__ out) {
    int t = blockIdx.x * 256 + threadIdx.x;   // 16384
    int b = t >> 10, o = t & 1023;
    float m = -INFINITY;
#pragma unroll 4
    for (int i = 0; i < 16; ++i)
        m = fmaxf(m, partial[(size_t)((b * 16 + i) * 1024) + o]);
    out[t] = m;
}

// ---------------------------------------------------------------- launch
extern "C" void kernel_launch(void* const* d_in, const int* in_sizes, int n_in,
                              void* d_out, int out_size, void* d_ws, size_t ws_size,
                              hipStream_t stream) {
    const float* x = (const float*)d_in[0];
    const float* w_edge = (const float*)d_in[1];
    const float* b_edge = (const float*)d_in[2];
    const float* w1 = (const float*)d_in[3];
    const float* b1 = (const float*)d_in[4];
    const float* w2 = (const float*)d_in[5];
    const float* b2 = (const float*)d_in[6];
    const float* w3 = (const float*)d_in[7];
    const float* b3 = (const float*)d_in[8];
    const float* w_final = (const float*)d_in[9];
    const float* b_final = (const float*)d_in[10];
    float* out = (float*)d_out;

    char* ws = (char*)d_ws;
    int* idx = (int*)ws;                                     // 2,621,440 B
    float* cat = (float*)(ws + 2621440);                     // 67,108,864 B  (PRE-BN)
    float* partial = (float*)(ws + 69730304);                // 1,048,576 B
    double* stats = (double*)(ws + 70778880);                // 8,192 B
    __hip_bfloat16* catb = (__hip_bfloat16*)(ws + 70787072); // 33,554,432 B  (post-BN bf16)
    __hip_bfloat16* wb = (__hip_bfloat16*)(ws + 104341504);  // 1,048,576 B

    double* st_e = stats;
    double* st_1 = stats + 128;
    double* st_2 = stats + 256;
    double* st_3 = stats + 512;
    const double ik = 1.0 / ((double)B_ * N_ * KNN);
    const double in_ = 1.0 / ((double)B_ * N_);

    hipMemsetAsync(stats, 0, 1024 * sizeof(double), stream);
    wconv_kernel<<<2048, 256, 0, stream>>>(w_final, wb);

    knn_kernel<<<B_ * 32, 256, 0, stream>>>(x, idx, w_edge, b_edge, cat, st_e);
    layer_kernel<64, 64, 4><<<(B_ * N_) / 64, 256, 0, stream>>>(
        cat, idx, w1, b1, st_e, ik, st_1, 0, 64);
    layer_kernel<64, 128, 8><<<(B_ * N_) / 64, 256, 0, stream>>>(
        cat, idx, w2, b2, st_1, in_, st_2, 64, 128);
    layer_kernel<128, 256, 16><<<(B_ * N_) / 64, 256, 0, stream>>>(
        cat, idx, w3, b3, st_2, in_, st_3, 128, 256);
    bnconv_kernel<<<(B_ * N_ * 128) / 256, 256, 0, stream>>>(
        cat, stats, (unsigned short*)catb, ik, in_);
    final_mfma_kernel<<<dim3(8, 256), 256, 0, stream>>>((const short*)catb, (const short*)wb,
                                                        b_final, partial);
    reduce_kernel<<<64, 256, 0, stream>>>(partial, out);
}

// Round 14
// 357.486 us; speedup vs baseline: 2.5201x; 2.5201x over previous
//
#include <hip/hip_runtime.h>
#include <hip/hip_bf16.h>
#include <math.h>

#define B_ 16
#define N_ 2048
#define KNN 20
#define SLOPE 0.2f
#define EPS_ 1e-5f

#define SEG 8
#define SEGLEN (N_ / SEG)   // 256
#define QPB 64              // queries per block (2 per thread)
#define CAP 64              // collected-candidate capacity per query

typedef __attribute__((ext_vector_type(8))) short short8;
typedef __attribute__((ext_vector_type(4))) float float4v;

// ------------------------------------------- kNN + EdgeConv (fused)
// scan1 is FULL-coverage (8 chunk-maxes of 32 = all 256 candidates/segment):
// R13's half-sampling loosened the threshold -> collected count blew past
// CAP -> serial fallback rescan dominated (661us). Full coverage restores
// the R12-validated ~25-30 collected (overflow provably rare; fallback kept
// as correctness net). Edge phase runs after the ladder from pts4 + stashed
// idx with identical FMA order to the old edge_kernel => bitwise-same cat.
__global__ __launch_bounds__(256, 2) void knn_kernel(const float* __restrict__ x,
                                                     int* __restrict__ idx,
                                                     const float* __restrict__ w_edge,
                                                     const float* __restrict__ b_edge,
                                                     float* __restrict__ cat,
                                                     double* __restrict__ stats) {
    __shared__ float4 pts4[N_];          // 32 KB: x,y,z,|p|^2
    __shared__ union {
        float thr[QPB * 24];             // scan-1 samples (dead after threshold)
        int sidx[QPB * KNN];             // stashed neighbor idx (ladder -> edge)
    } u2;
    __shared__ float tq[QPB];
    __shared__ int cnt[QPB];
    __shared__ float lv[QPB * CAP];      // 16 KB
    __shared__ int   li[QPB * CAP];      // 16 KB
    __shared__ float ws[64 * 6];
    __shared__ float bs[64];
    __shared__ float s_sum[64], s_sq[64];

    const int b = blockIdx.x >> 5;       // 32 blocks per batch
    const int qb = blockIdx.x & 31;
    const float* xb = x + (size_t)b * N_ * 3;
    for (int i = threadIdx.x; i < N_; i += 256) {
        float xv = xb[i * 3], yv = xb[i * 3 + 1], zv = xb[i * 3 + 2];
        pts4[i] = make_float4(xv, yv, zv, xv * xv + yv * yv + zv * zv);
    }
    for (int i = threadIdx.x; i < 64 * 6; i += 256) ws[i] = w_edge[i];
    if (threadIdx.x < QPB) {
        cnt[threadIdx.x] = 0;
        bs[threadIdx.x] = b_edge[threadIdx.x];
        s_sum[threadIdx.x] = 0.f; s_sq[threadIdx.x] = 0.f;
    }
    __syncthreads();

    const int s = threadIdx.x >> 5;      // segment 0..7 (uniform per half-wave)
    const int qs = threadIdx.x & 31;     // query-pair slot
    const int q0 = qs * 2, q1 = q0 + 1;
    const int n0 = qb * QPB + q0;
    const float4 pa = pts4[n0];
    const float4 pb = pts4[n0 + 1];
    const int m0 = s * SEGLEN;

    // ---- scan 1: 8 chunk-maxes of 32 (FULL coverage), 8-deep load batching
    float ca[8], cb[8];
#pragma unroll
    for (int c = 0; c < 8; ++c) {
        float va0 = -INFINITY, va1 = -INFINITY;
        float vb0 = -INFINITY, vb1 = -INFINITY;
        for (int g = 0; g < 4; ++g) {
            float4 r[8];
#pragma unroll
            for (int j = 0; j < 8; ++j) r[j] = pts4[m0 + c * 32 + g * 8 + j];
#pragma unroll
            for (int j = 0; j < 8; ++j) {
                const float da = 2.f * (pa.x * r[j].x + pa.y * r[j].y + pa.z * r[j].z)
                                 - pa.w - r[j].w;
                const float db = 2.f * (pb.x * r[j].x + pb.y * r[j].y + pb.z * r[j].z)
                                 - pb.w - r[j].w;
                if (j & 1) { va1 = fmaxf(va1, da); vb1 = fmaxf(vb1, db); }
                else       { va0 = fmaxf(va0, da); vb0 = fmaxf(vb0, db); }
            }
        }
        ca[c] = fmaxf(va0, va1); cb[c] = fmaxf(vb0, vb1);
    }
    // top-3 of the 8 chunk maxes per query (branch-free carried min/max)
    {
        float t0 = -INFINITY, t1 = -INFINITY, t2 = -INFINITY;
        float u0 = -INFINITY, u1 = -INFINITY, u2v = -INFINITY;
#pragma unroll
        for (int c = 0; c < 8; ++c) {
            float v = ca[c];
            float r0 = fminf(t0, v); t0 = fmaxf(t0, v);
            float r1 = fminf(t1, r0); t1 = fmaxf(t1, r0);
            t2 = fmaxf(t2, r1);
            float w = cb[c];
            float s0 = fminf(u0, w); u0 = fmaxf(u0, w);
            float s1 = fminf(u1, s0); u1 = fmaxf(u1, s0);
            u2v = fmaxf(u2v, s1);
        }
        u2.thr[q0 * 24 + s * 3 + 0] = t0;
        u2.thr[q0 * 24 + s * 3 + 1] = t1;
        u2.thr[q0 * 24 + s * 3 + 2] = t2;
        u2.thr[q1 * 24 + s * 3 + 0] = u0;
        u2.thr[q1 * 24 + s * 3 + 1] = u1;
        u2.thr[q1 * 24 + s * 3 + 2] = u2v;
    }
    __syncthreads();

    // ---- threshold: 20th largest of 24 = 5th smallest; conservative epsilon
    if (threadIdx.x < QPB) {
        const int qq = threadIdx.x;
        float s0 = INFINITY, s1 = INFINITY, s2 = INFINITY, s3 = INFINITY, s4 = INFINITY;
#pragma unroll
        for (int j = 0; j < 24; ++j) {
            float c = u2.thr[qq * 24 + j];
            float u;
            u = fminf(s0, c); c = fmaxf(s0, c); s0 = u;
            u = fminf(s1, c); c = fmaxf(s1, c); s1 = u;
            u = fminf(s2, c); c = fmaxf(s2, c); s2 = u;
            u = fminf(s3, c); c = fmaxf(s3, c); s3 = u;
            s4 = fminf(s4, c);
        }
        tq[qq] = s4 - (fabsf(s4) * 1e-6f + 1e-6f);
    }
    __syncthreads();

    // ---- scan 2: collect candidates >= t for both queries (8-deep batches)
    const float ta = tq[q0];
    const float tb = tq[q1];
    for (int g = 0; g < 32; ++g) {
        float4 r[8];
#pragma unroll
        for (int j = 0; j < 8; ++j) r[j] = pts4[m0 + g * 8 + j];
#pragma unroll
        for (int j = 0; j < 8; ++j) {
            const int m = m0 + g * 8 + j;
            const float da = 2.f * (pa.x * r[j].x + pa.y * r[j].y + pa.z * r[j].z)
                             - pa.w - r[j].w;
            const float db = 2.f * (pb.x * r[j].x + pb.y * r[j].y + pb.z * r[j].z)
                             - pb.w - r[j].w;
            if (da >= ta) {
                int pos = atomicAdd(&cnt[q0], 1);
                if (pos < CAP) { lv[q0 * CAP + pos] = da; li[q0 * CAP + pos] = m; }
            }
            if (db >= tb) {
                int pos = atomicAdd(&cnt[q1], 1);
                if (pos < CAP) { lv[q1 * CAP + pos] = db; li[q1 * CAP + pos] = m; }
            }
        }
    }
    __syncthreads();   // thr is dead from here; sidx overlay becomes safe

    // ---- exact top-20 per query, stash idx for edge phase
    if (threadIdx.x < QPB) {
        const int qq = threadIdx.x;
        const int nn = qb * QPB + qq;
        int* op = idx + (size_t)(b * N_ + nn) * KNN;
        float vals[KNN]; int inds[KNN];
#pragma unroll
        for (int j = 0; j < KNN; ++j) { vals[j] = -INFINITY; inds[j] = 0; }
        const int c = cnt[qq];
        if (c <= CAP) {
            for (int j = 0; j < c; ++j) {
                const float v = lv[qq * CAP + j];
                if (v > vals[KNN - 1]) {
                    float cv = v; int ci = li[qq * CAP + j];
#pragma unroll
                    for (int k = 0; k < KNN; ++k) {
                        const bool sw = cv > vals[k];
                        const float tv = vals[k]; const int ti = inds[k];
                        vals[k] = sw ? cv : tv;  inds[k] = sw ? ci : ti;
                        cv      = sw ? tv : cv;  ci      = sw ? ti : ci;
                    }
                }
            }
        } else {
            // overflow fallback: exact full rescan (provably rare)
            const float4 pq2 = pts4[nn];
            for (int m = 0; m < N_; ++m) {
                const float4 p = pts4[m];
                const float d = 2.f * (pq2.x * p.x + pq2.y * p.y + pq2.z * p.z)
                                - pq2.w - p.w;
                if (d > vals[KNN - 1]) {
                    float cv = d; int ci = m;
#pragma unroll
                    for (int k = 0; k < KNN; ++k) {
                        const bool sw = cv > vals[k];
                        const float tv = vals[k]; const int ti = inds[k];
                        vals[k] = sw ? cv : tv;  inds[k] = sw ? ci : ti;
                        cv      = sw ? tv : cv;  ci      = sw ? ti : ci;
                    }
                }
            }
        }
#pragma unroll
        for (int j = 0; j < KNN; ++j) {
            op[j] = inds[j];
            u2.sidx[qq * KNN + j] = inds[j];
        }
    }
    __syncthreads();

    // ---- EdgeConv phase (identical arithmetic to the old edge_kernel)
    {
        const int p = threadIdx.x >> 2;     // point 0..63
        const int cg = threadIdx.x & 3;     // channel group (16 ch)
        const int n = qb * QPB + p;
        const float4 ctr = pts4[n];
        const float cx = ctr.x, cy = ctr.y, cz = ctr.z;

        float maxv[16], sum[16], sq[16];
#pragma unroll
        for (int i = 0; i < 16; ++i) { maxv[i] = -INFINITY; sum[i] = 0.f; sq[i] = 0.f; }

        for (int k = 0; k < KNN; ++k) {
            const int j = u2.sidx[p * KNN + k];
            const float4 nb = pts4[j];
            const float dx = nb.x - cx, dy = nb.y - cy, dz = nb.z - cz;
#pragma unroll
            for (int i = 0; i < 16; ++i) {
                const int o = cg * 16 + i;
                const float* wr = &ws[o * 6];
                float h = bs[o] + wr[0] * dx + wr[1] * dy + wr[2] * dz
                                + wr[3] * cx + wr[4] * cy + wr[5] * cz;
                sum[i] += h; sq[i] += h * h;
                maxv[i] = fmaxf(maxv[i], h);
            }
        }

        float* cp = cat + (size_t)(b * N_ + n) * 512 + cg * 16;
#pragma unroll
        for (int i4 = 0; i4 < 4; ++i4)
            *(float4*)&cp[i4 * 4] = make_float4(maxv[i4 * 4], maxv[i4 * 4 + 1],
                                                maxv[i4 * 4 + 2], maxv[i4 * 4 + 3]);
#pragma unroll
        for (int i = 0; i < 16; ++i) {
            atomicAdd(&s_sum[cg * 16 + i], sum[i]);
            atomicAdd(&s_sq[cg * 16 + i], sq[i]);
        }
    }
    __syncthreads();
    if (threadIdx.x < 64) {
        atomicAdd(&stats[threadIdx.x], (double)s_sum[threadIdx.x]);
        atomicAdd(&stats[64 + threadIdx.x], (double)s_sq[threadIdx.x]);
    }
}

// ----------------------------------------------------- w_final -> bf16
__global__ __launch_bounds__(256) void wconv_kernel(const float* __restrict__ w,
                                                    __hip_bfloat16* __restrict__ wb) {
    int t = blockIdx.x * 256 + threadIdx.x;   // 1024*512
    wb[t] = __float2bfloat16(w[t]);
}

// -------------------- graph max-pool + input-BN+LReLU + 1x1 conv + stats
// XCD-swizzled block decode: batch = blockIdx & 15 (all 32 blocks of a batch
// share one XCD with round-robin mapping -> neighbor slab stays L2-resident).
template <int CIN, int COUT, int PT>
__global__ __launch_bounds__(256) void layer_kernel(float* __restrict__ cat,
                                                    const int* __restrict__ idx,
                                                    const float* __restrict__ w,
                                                    const float* __restrict__ bias,
                                                    const double* __restrict__ stats_in,
                                                    double invcnt_in,
                                                    double* __restrict__ stats_out,
                                                    int off_in, int off_out) {
    constexpr int P = 64;
    constexpr int LDC = CIN + 4;        // g row stride, 16B-aligned
    constexpr int WS = COUT + 4;        // wt row stride
    constexpr int NCG = CIN / 4;        // channel float4 groups
    constexpr int PPAR = 256 / NCG;     // points gathered in parallel
    constexpr int NOG = COUT / 4;       // output quad groups
    static_assert(NOG * (P / PT) == 256, "thread mapping");

    __shared__ float g[P * LDC];
    __shared__ float wt[16 * WS];       // [cc][o] — lane-contiguous, conflict-free
    __shared__ float s_sum[COUT], s_sq[COUT];

    const int b = blockIdx.x & 15;      // XCD swizzle: batch fast-varying
    const int pb = blockIdx.x >> 4;     // 0..31
    const int pt0 = b * N_ + pb * P;    // flattened b*N+n

    // ---- gather + max + input BN/LReLU
    {
        const int cg = threadIdx.x % NCG;
        const int pp = threadIdx.x / NCG;
        float mean[4], inv[4];
#pragma unroll
        for (int j = 0; j < 4; ++j) {
            const double mu = stats_in[cg * 4 + j] * invcnt_in;
            const double e2 = stats_in[CIN + cg * 4 + j] * invcnt_in;
            const float var = (float)(e2 - mu * mu);
            mean[j] = (float)mu;
            inv[j] = rsqrtf(var + EPS_);
        }
        for (int p = pp; p < P; p += PPAR) {
            const int* ip = idx + (size_t)(pt0 + p) * KNN;
            float4 m = make_float4(-INFINITY, -INFINITY, -INFINITY, -INFINITY);
#pragma unroll
            for (int k = 0; k < KNN; ++k) {
                const int j = ip[k];
                const float4 v = *(const float4*)&cat[(size_t)(b * N_ + j) * 512 + off_in + cg * 4];
                m.x = fmaxf(m.x, v.x); m.y = fmaxf(m.y, v.y);
                m.z = fmaxf(m.z, v.z); m.w = fmaxf(m.w, v.w);
            }
            float4 r;
            r.x = (m.x - mean[0]) * inv[0]; r.x = r.x >= 0.f ? r.x : SLOPE * r.x;
            r.y = (m.y - mean[1]) * inv[1]; r.y = r.y >= 0.f ? r.y : SLOPE * r.y;
            r.z = (m.z - mean[2]) * inv[2]; r.z = r.z >= 0.f ? r.z : SLOPE * r.z;
            r.w = (m.w - mean[3]) * inv[3]; r.w = r.w >= 0.f ? r.w : SLOPE * r.w;
            *(float4*)&g[p * LDC + cg * 4] = r;
        }
    }
    if (threadIdx.x < COUT) { s_sum[threadIdx.x] = 0.f; s_sq[threadIdx.x] = 0.f; }

    // ---- conv: 4 outs x PT points per thread
    const int og = threadIdx.x % NOG;
    const int pg = threadIdx.x / NOG;
    const int o0 = og * 4, p0 = pg * PT;

    float acc[4][PT];
#pragma unroll
    for (int i = 0; i < 4; ++i)
#pragma unroll
        for (int j = 0; j < PT; ++j) acc[i][j] = 0.f;

    for (int c0 = 0; c0 < CIN; c0 += 16) {
        __syncthreads();
        for (int i = threadIdx.x; i < COUT * 16; i += 256) {
            int o = i >> 4, cc = i & 15;
            wt[cc * WS + o] = w[(size_t)o * CIN + c0 + cc];
        }
        __syncthreads();
#pragma unroll
        for (int ccq = 0; ccq < 4; ++ccq) {
            const float4 w0 = *(const float4*)&wt[(ccq * 4 + 0) * WS + o0];
            const float4 w1 = *(const float4*)&wt[(ccq * 4 + 1) * WS + o0];
            const float4 w2 = *(const float4*)&wt[(ccq * 4 + 2) * WS + o0];
            const float4 w3 = *(const float4*)&wt[(ccq * 4 + 3) * WS + o0];
#pragma unroll
            for (int p = 0; p < PT; ++p) {
                const float4 gv = *(const float4*)&g[(p0 + p) * LDC + c0 + ccq * 4];
                acc[0][p] += w0.x * gv.x; acc[0][p] += w1.x * gv.y;
                acc[0][p] += w2.x * gv.z; acc[0][p] += w3.x * gv.w;
                acc[1][p] += w0.y * gv.x; acc[1][p] += w1.y * gv.y;
                acc[1][p] += w2.y * gv.z; acc[1][p] += w3.y * gv.w;
                acc[2][p] += w0.z * gv.x; acc[2][p] += w1.z * gv.y;
                acc[2][p] += w2.z * gv.z; acc[2][p] += w3.z * gv.w;
                acc[3][p] += w0.w * gv.x; acc[3][p] += w1.w * gv.y;
                acc[3][p] += w2.w * gv.z; acc[3][p] += w3.w * gv.w;
            }
        }
    }

    // ---- epilogue: bias, stats, contiguous float4 stores (PRE-BN output)
    const float4 bv = *(const float4*)&bias[o0];
    float lsum[4] = {0.f, 0.f, 0.f, 0.f}, lsq[4] = {0.f, 0.f, 0.f, 0.f};
#pragma unroll
    for (int p = 0; p < PT; ++p) {
        float4 hv;
        hv.x = acc[0][p] + bv.x; hv.y = acc[1][p] + bv.y;
        hv.z = acc[2][p] + bv.z; hv.w = acc[3][p] + bv.w;
        lsum[0] += hv.x; lsq[0] += hv.x * hv.x;
        lsum[1] += hv.y; lsq[1] += hv.y * hv.y;
        lsum[2] += hv.z; lsq[2] += hv.z * hv.z;
        lsum[3] += hv.w; lsq[3] += hv.w * hv.w;
        *(float4*)&cat[(size_t)(pt0 + p0 + p) * 512 + off_out + o0] = hv;
    }
#pragma unroll
    for (int i = 0; i < 4; ++i) {
        atomicAdd(&s_sum[o0 + i], lsum[i]);
        atomicAdd(&s_sq[o0 + i], lsq[i]);
    }
    __syncthreads();
    if (threadIdx.x < COUT) {
        atomicAdd(&stats_out[threadIdx.x], (double)s_sum[threadIdx.x]);
        atomicAdd(&stats_out[COUT + threadIdx.x], (double)s_sq[threadIdx.x]);
    }
}

// ------------- fused BN+LReLU -> bf16 for all 512 channels (final GEMM input)
__global__ __launch_bounds__(256) void bnconv_kernel(const float* __restrict__ cat,
                                                     const double* __restrict__ stats,
                                                     unsigned short* __restrict__ catb,
                                                     double ik, double in_) {
    const int t = blockIdx.x * 256 + threadIdx.x;   // over 32768*128 float4s
    const int pn = t >> 7;
    const int c = (t & 127) * 4;

    const double* sp; const double* qp; double icnt;
    if (c < 64)       { sp = stats + c;             qp = stats + 64 + c;        icnt = ik; }
    else if (c < 128) { sp = stats + 128 + (c - 64);  qp = stats + 192 + (c - 64);  icnt = in_; }
    else if (c < 256) { sp = stats + 256 + (c - 128); qp = stats + 384 + (c - 128); icnt = in_; }
    else              { sp = stats + 512 + (c - 256); qp = stats + 768 + (c - 256); icnt = in_; }

    const float4 v = *(const float4*)&cat[(size_t)pn * 512 + c];
    float r[4]; const float vv[4] = {v.x, v.y, v.z, v.w};
#pragma unroll
    for (int j = 0; j < 4; ++j) {
        const double mu = sp[j] * icnt;
        const double e2 = qp[j] * icnt;
        const float var = (float)(e2 - mu * mu);
        const float inv = rsqrtf(var + EPS_);
        float x = (vv[j] - (float)mu) * inv;
        r[j] = x >= 0.f ? x : SLOPE * x;
    }
    ushort4 o;
    __hip_bfloat16 h0 = __float2bfloat16(r[0]); o.x = *(unsigned short*)&h0;
    __hip_bfloat16 h1 = __float2bfloat16(r[1]); o.y = *(unsigned short*)&h1;
    __hip_bfloat16 h2 = __float2bfloat16(r[2]); o.z = *(unsigned short*)&h2;
    __hip_bfloat16 h3 = __float2bfloat16(r[3]); o.w = *(unsigned short*)&h3;
    *(ushort4*)&catb[(size_t)pn * 512 + c] = o;
}

// -------------- final GEMM via bf16 MFMA + bias + max-over-n (register staging)
__global__ __launch_bounds__(256) void final_mfma_kernel(const short* __restrict__ catb,
                                                         const short* __restrict__ wb,
                                                         const float* __restrict__ bias,
                                                         float* __restrict__ partial) {
    constexpr int LDK = 72;              // 64 + 8 pad: 144 B row stride (16B-aligned)
    __shared__ short As[128 * LDK];
    __shared__ short Bs[128 * LDK];
    __shared__ float red[256];

    const int ob = blockIdx.x;     // 0..7, fast-varying: A tile stays L2/LLC-hot
    const int pblk = blockIdx.y;   // 0..255
    const int pt0 = pblk * 128;

    const int wid = threadIdx.x >> 6;
    const int lane = threadIdx.x & 63;
    const int wm = wid >> 1, wn = wid & 1;   // 2x2 wave grid -> 64x64 per wave
    const int lm = lane & 15, g = lane >> 4;

    const int srow = threadIdx.x >> 1;
    const int scg = (threadIdx.x & 1) * 32;
    const short* ga = catb + (size_t)(pt0 + srow) * 512 + scg;
    const short* gb = wb + (size_t)(ob * 128 + srow) * 512 + scg;
    short* la = As + srow * LDK + scg;
    short* lb = Bs + srow * LDK + scg;

    float4v acc[4][4];
#pragma unroll
    for (int i = 0; i < 4; ++i)
#pragma unroll
        for (int j = 0; j < 4; ++j) acc[i][j] = {0.f, 0.f, 0.f, 0.f};

    short8 ra[4], rb[4];
#pragma unroll
    for (int j = 0; j < 4; ++j) {
        ra[j] = *(const short8*)(ga + j * 8);
        rb[j] = *(const short8*)(gb + j * 8);
    }

    for (int step = 0; step < 8; ++step) {
        __syncthreads();
#pragma unroll
        for (int j = 0; j < 4; ++j) {
            *(short8*)(la + j * 8) = ra[j];
            *(short8*)(lb + j * 8) = rb[j];
        }
        __syncthreads();
        if (step < 7) {
            const int c1 = (step + 1) * 64;
#pragma unroll
            for (int j = 0; j < 4; ++j) {
                ra[j] = *(const short8*)(ga + c1 + j * 8);
                rb[j] = *(const short8*)(gb + c1 + j * 8);
            }
        }
#pragma unroll
        for (int kk = 0; kk < 2; ++kk) {
            short8 a[4], b[4];
#pragma unroll
            for (int t = 0; t < 4; ++t) {
                a[t] = *(const short8*)&As[(wm * 64 + t * 16 + lm) * LDK + kk * 32 + g * 8];
                b[t] = *(const short8*)&Bs[(wn * 64 + t * 16 + lm) * LDK + kk * 32 + g * 8];
            }
#pragma unroll
            for (int mt = 0; mt < 4; ++mt)
#pragma unroll
                for (int nt = 0; nt < 4; ++nt)
                    acc[mt][nt] = __builtin_amdgcn_mfma_f32_16x16x32_bf16(
                        a[mt], b[nt], acc[mt][nt], 0, 0, 0);
        }
    }

    float cm[4];
#pragma unroll
    for (int nt = 0; nt < 4; ++nt) {
        float m = -INFINITY;
#pragma unroll
        for (int mt = 0; mt < 4; ++mt)
#pragma unroll
            for (int r = 0; r < 4; ++r) m = fmaxf(m, acc[mt][nt][r]);
        m = fmaxf(m, __shfl_xor(m, 16, 64));
        m = fmaxf(m, __shfl_xor(m, 32, 64));
        cm[nt] = m;
    }
    __syncthreads();
    if (lane < 16) {
#pragma unroll
        for (int nt = 0; nt < 4; ++nt)
            red[wm * 128 + wn * 64 + nt * 16 + lane] = cm[nt];
    }
    __syncthreads();
    if (threadIdx.x < 128) {
        const int o = threadIdx.x;
        float v = fmaxf(red[o], red[128 + o]) + bias[ob * 128 + o];
        partial[(size_t)pblk * 1024 + ob * 128 + o] = v;
    }
}

// ----------------------------------------------------------- final reduce
__global__ __launch_bounds__(256) void reduce_kernel(const float* __restrict__ partial,
                                                     float* __restrict__ out) {
    int t = blockIdx.x * 256 + threadIdx.x;   // 16384
    int b = t >> 10, o = t & 1023;
    float m = -INFINITY;
#pragma unroll 4
    for (int i = 0; i < 16; ++i)
        m = fmaxf(m, partial[(size_t)((b * 16 + i) * 1024) + o]);
    out[t] = m;
}

// ---------------------------------------------------------------- launch
extern "C" void kernel_launch(void* const* d_in, const int* in_sizes, int n_in,
                              void* d_out, int out_size, void* d_ws, size_t ws_size,
                              hipStream_t stream) {
    const float* x = (const float*)d_in[0];
    const float* w_edge = (const float*)d_in[1];
    const float* b_edge = (const float*)d_in[2];
    const float* w1 = (const float*)d_in[3];
    const float* b1 = (const float*)d_in[4];
    const float* w2 = (const float*)d_in[5];
    const float* b2 = (const float*)d_in[6];
    const float* w3 = (const float*)d_in[7];
    const float* b3 = (const float*)d_in[8];
    const float* w_final = (const float*)d_in[9];
    const float* b_final = (const float*)d_in[10];
    float* out = (float*)d_out;

    char* ws = (char*)d_ws;
    int* idx = (int*)ws;                                     // 2,621,440 B
    float* cat = (float*)(ws + 2621440);                     // 67,108,864 B  (PRE-BN)
    float* partial = (float*)(ws + 69730304);                // 1,048,576 B
    double* stats = (double*)(ws + 70778880);                // 8,192 B
    __hip_bfloat16* catb = (__hip_bfloat16*)(ws + 70787072); // 33,554,432 B  (post-BN bf16)
    __hip_bfloat16* wb = (__hip_bfloat16*)(ws + 104341504);  // 1,048,576 B

    double* st_e = stats;
    double* st_1 = stats + 128;
    double* st_2 = stats + 256;
    double* st_3 = stats + 512;
    const double ik = 1.0 / ((double)B_ * N_ * KNN);
    const double in_ = 1.0 / ((double)B_ * N_);

    hipMemsetAsync(stats, 0, 1024 * sizeof(double), stream);
    wconv_kernel<<<2048, 256, 0, stream>>>(w_final, wb);

    knn_kernel<<<B_ * 32, 256, 0, stream>>>(x, idx, w_edge, b_edge, cat, st_e);
    layer_kernel<64, 64, 4><<<(B_ * N_) / 64, 256, 0, stream>>>(
        cat, idx, w1, b1, st_e, ik, st_1, 0, 64);
    layer_kernel<64, 128, 8><<<(B_ * N_) / 64, 256, 0, stream>>>(
        cat, idx, w2, b2, st_1, in_, st_2, 64, 128);
    layer_kernel<128, 256, 16><<<(B_ * N_) / 64, 256, 0, stream>>>(
        cat, idx, w3, b3, st_2, in_, st_3, 128, 256);
    bnconv_kernel<<<(B_ * N_ * 128) / 256, 256, 0, stream>>>(
        cat, stats, (unsigned short*)catb, ik, in_);
    final_mfma_kernel<<<dim3(8, 256), 256, 0, stream>>>((const short*)catb, (const short*)wb,
                                                        b_final, partial);
    reduce_kernel<<<64, 256, 0, stream>>>(partial, out);
}

// Round 15
// 351.762 us; speedup vs baseline: 2.5611x; 1.0163x over previous
//
#include <hip/hip_runtime.h>
#include <hip/hip_bf16.h>
#include <math.h>

#define B_ 16
#define N_ 2048
#define KNN 20
#define SLOPE 0.2f
#define EPS_ 1e-5f

#define SEG 8
#define SEGLEN (N_ / SEG)   // 256
#define QPB 64              // queries per block (2 per thread)
#define CAP 64              // collected-candidate capacity per query

typedef __attribute__((ext_vector_type(8))) short short8;
typedef __attribute__((ext_vector_type(4))) float float4v;

// ------------------------------------------- kNN + EdgeConv (fused)
// Full-coverage scan1 (R14-validated threshold contract). LDS diet: no lv
// array (ladder recomputes d from pts4), collected indices stored as ushort
// -> ~49 KB LDS -> 3 blocks/CU (was 74.7 KB / 2). Edge phase precomputes
// co[i] = bias + w.ctr per point (fewer VALU per (k,i)).
__global__ __launch_bounds__(256, 3) void knn_kernel(const float* __restrict__ x,
                                                     int* __restrict__ idx,
                                                     const float* __restrict__ w_edge,
                                                     const float* __restrict__ b_edge,
                                                     float* __restrict__ cat,
                                                     double* __restrict__ stats) {
    __shared__ float4 pts4[N_];          // 32 KB: x,y,z,|p|^2
    __shared__ union {
        float thr[QPB * 24];             // scan-1 samples (dead after threshold)
        int sidx[QPB * KNN];             // stashed neighbor idx (ladder -> edge)
    } u2;
    __shared__ float tq[QPB];
    __shared__ int cnt[QPB];
    __shared__ unsigned short li[QPB * CAP];   // 8 KB collected indices
    __shared__ float ws[64 * 6];
    __shared__ float bs[64];
    __shared__ float s_sum[64], s_sq[64];

    const int b = blockIdx.x >> 5;       // 32 blocks per batch
    const int qb = blockIdx.x & 31;
    const float* xb = x + (size_t)b * N_ * 3;
    for (int i = threadIdx.x; i < N_; i += 256) {
        float xv = xb[i * 3], yv = xb[i * 3 + 1], zv = xb[i * 3 + 2];
        pts4[i] = make_float4(xv, yv, zv, xv * xv + yv * yv + zv * zv);
    }
    for (int i = threadIdx.x; i < 64 * 6; i += 256) ws[i] = w_edge[i];
    if (threadIdx.x < QPB) {
        cnt[threadIdx.x] = 0;
        bs[threadIdx.x] = b_edge[threadIdx.x];
        s_sum[threadIdx.x] = 0.f; s_sq[threadIdx.x] = 0.f;
    }
    __syncthreads();

    const int s = threadIdx.x >> 5;      // segment 0..7 (uniform per half-wave)
    const int qs = threadIdx.x & 31;     // query-pair slot
    const int q0 = qs * 2, q1 = q0 + 1;
    const int n0 = qb * QPB + q0;
    const float4 pa = pts4[n0];
    const float4 pb = pts4[n0 + 1];
    const int m0 = s * SEGLEN;

    // ---- scan 1: 8 chunk-maxes of 32 (FULL coverage), 8-deep load batching
    float ca[8], cb[8];
#pragma unroll
    for (int c = 0; c < 8; ++c) {
        float va0 = -INFINITY, va1 = -INFINITY;
        float vb0 = -INFINITY, vb1 = -INFINITY;
        for (int g = 0; g < 4; ++g) {
            float4 r[8];
#pragma unroll
            for (int j = 0; j < 8; ++j) r[j] = pts4[m0 + c * 32 + g * 8 + j];
#pragma unroll
            for (int j = 0; j < 8; ++j) {
                const float da = 2.f * (pa.x * r[j].x + pa.y * r[j].y + pa.z * r[j].z)
                                 - pa.w - r[j].w;
                const float db = 2.f * (pb.x * r[j].x + pb.y * r[j].y + pb.z * r[j].z)
                                 - pb.w - r[j].w;
                if (j & 1) { va1 = fmaxf(va1, da); vb1 = fmaxf(vb1, db); }
                else       { va0 = fmaxf(va0, da); vb0 = fmaxf(vb0, db); }
            }
        }
        ca[c] = fmaxf(va0, va1); cb[c] = fmaxf(vb0, vb1);
    }
    // top-3 of the 8 chunk maxes per query (branch-free carried min/max)
    {
        float t0 = -INFINITY, t1 = -INFINITY, t2 = -INFINITY;
        float u0 = -INFINITY, u1 = -INFINITY, u2v = -INFINITY;
#pragma unroll
        for (int c = 0; c < 8; ++c) {
            float v = ca[c];
            float r0 = fminf(t0, v); t0 = fmaxf(t0, v);
            float r1 = fminf(t1, r0); t1 = fmaxf(t1, r0);
            t2 = fmaxf(t2, r1);
            float w = cb[c];
            float s0 = fminf(u0, w); u0 = fmaxf(u0, w);
            float s1 = fminf(u1, s0); u1 = fmaxf(u1, s0);
            u2v = fmaxf(u2v, s1);
        }
        u2.thr[q0 * 24 + s * 3 + 0] = t0;
        u2.thr[q0 * 24 + s * 3 + 1] = t1;
        u2.thr[q0 * 24 + s * 3 + 2] = t2;
        u2.thr[q1 * 24 + s * 3 + 0] = u0;
        u2.thr[q1 * 24 + s * 3 + 1] = u1;
        u2.thr[q1 * 24 + s * 3 + 2] = u2v;
    }
    __syncthreads();

    // ---- threshold: 20th largest of 24 = 5th smallest; conservative epsilon
    if (threadIdx.x < QPB) {
        const int qq = threadIdx.x;
        float s0 = INFINITY, s1 = INFINITY, s2 = INFINITY, s3 = INFINITY, s4 = INFINITY;
#pragma unroll
        for (int j = 0; j < 24; ++j) {
            float c = u2.thr[qq * 24 + j];
            float u;
            u = fminf(s0, c); c = fmaxf(s0, c); s0 = u;
            u = fminf(s1, c); c = fmaxf(s1, c); s1 = u;
            u = fminf(s2, c); c = fmaxf(s2, c); s2 = u;
            u = fminf(s3, c); c = fmaxf(s3, c); s3 = u;
            s4 = fminf(s4, c);
        }
        tq[qq] = s4 - (fabsf(s4) * 1e-6f + 1e-6f);
    }
    __syncthreads();

    // ---- scan 2: collect candidate indices >= t (8-deep batches)
    const float ta = tq[q0];
    const float tb = tq[q1];
    for (int g = 0; g < 32; ++g) {
        float4 r[8];
#pragma unroll
        for (int j = 0; j < 8; ++j) r[j] = pts4[m0 + g * 8 + j];
#pragma unroll
        for (int j = 0; j < 8; ++j) {
            const int m = m0 + g * 8 + j;
            const float da = 2.f * (pa.x * r[j].x + pa.y * r[j].y + pa.z * r[j].z)
                             - pa.w - r[j].w;
            const float db = 2.f * (pb.x * r[j].x + pb.y * r[j].y + pb.z * r[j].z)
                             - pb.w - r[j].w;
            if (da >= ta) {
                int pos = atomicAdd(&cnt[q0], 1);
                if (pos < CAP) li[q0 * CAP + pos] = (unsigned short)m;
            }
            if (db >= tb) {
                int pos = atomicAdd(&cnt[q1], 1);
                if (pos < CAP) li[q1 * CAP + pos] = (unsigned short)m;
            }
        }
    }
    __syncthreads();   // thr is dead from here; sidx overlay becomes safe

    // ---- exact top-20 per query (recompute d from pts4), stash idx for edge
    if (threadIdx.x < QPB) {
        const int qq = threadIdx.x;
        const int nn = qb * QPB + qq;
        int* op = idx + (size_t)(b * N_ + nn) * KNN;
        const float4 pq2 = pts4[nn];
        float vals[KNN]; int inds[KNN];
#pragma unroll
        for (int j = 0; j < KNN; ++j) { vals[j] = -INFINITY; inds[j] = 0; }
        const int c = cnt[qq];
        if (c <= CAP) {
            for (int j = 0; j < c; ++j) {
                const int m = li[qq * CAP + j];
                const float4 p = pts4[m];
                const float v = 2.f * (pq2.x * p.x + pq2.y * p.y + pq2.z * p.z)
                                - pq2.w - p.w;
                if (v > vals[KNN - 1]) {
                    float cv = v; int ci = m;
#pragma unroll
                    for (int k = 0; k < KNN; ++k) {
                        const bool sw = cv > vals[k];
                        const float tv = vals[k]; const int ti = inds[k];
                        vals[k] = sw ? cv : tv;  inds[k] = sw ? ci : ti;
                        cv      = sw ? tv : cv;  ci      = sw ? ti : ci;
                    }
                }
            }
        } else {
            // overflow fallback: exact full rescan (provably rare)
            for (int m = 0; m < N_; ++m) {
                const float4 p = pts4[m];
                const float d = 2.f * (pq2.x * p.x + pq2.y * p.y + pq2.z * p.z)
                                - pq2.w - p.w;
                if (d > vals[KNN - 1]) {
                    float cv = d; int ci = m;
#pragma unroll
                    for (int k = 0; k < KNN; ++k) {
                        const bool sw = cv > vals[k];
                        const float tv = vals[k]; const int ti = inds[k];
                        vals[k] = sw ? cv : tv;  inds[k] = sw ? ci : ti;
                        cv      = sw ? tv : cv;  ci      = sw ? ti : ci;
                    }
                }
            }
        }
#pragma unroll
        for (int j = 0; j < KNN; ++j) {
            op[j] = inds[j];
            u2.sidx[qq * KNN + j] = inds[j];
        }
    }
    __syncthreads();

    // ---- EdgeConv phase: co[i] = bias + w.ctr hoisted out of the k-loop
    {
        const int p = threadIdx.x >> 2;     // point 0..63
        const int cg = threadIdx.x & 3;     // channel group (16 ch)
        const int n = qb * QPB + p;
        const float4 ctr = pts4[n];
        const float cx = ctr.x, cy = ctr.y, cz = ctr.z;

        float co[16], maxv[16], sum[16], sq[16];
#pragma unroll
        for (int i = 0; i < 16; ++i) {
            const int o = cg * 16 + i;
            const float* wr = &ws[o * 6];
            co[i] = bs[o] + wr[3] * cx + wr[4] * cy + wr[5] * cz;
            maxv[i] = -INFINITY; sum[i] = 0.f; sq[i] = 0.f;
        }

        for (int k = 0; k < KNN; ++k) {
            const int j = u2.sidx[p * KNN + k];
            const float4 nb = pts4[j];
            const float dx = nb.x - cx, dy = nb.y - cy, dz = nb.z - cz;
#pragma unroll
            for (int i = 0; i < 16; ++i) {
                const float* wr = &ws[(cg * 16 + i) * 6];
                float h = co[i] + wr[0] * dx + wr[1] * dy + wr[2] * dz;
                sum[i] += h; sq[i] += h * h;
                maxv[i] = fmaxf(maxv[i], h);
            }
        }

        float* cp = cat + (size_t)(b * N_ + n) * 512 + cg * 16;
#pragma unroll
        for (int i4 = 0; i4 < 4; ++i4)
            *(float4*)&cp[i4 * 4] = make_float4(maxv[i4 * 4], maxv[i4 * 4 + 1],
                                                maxv[i4 * 4 + 2], maxv[i4 * 4 + 3]);
#pragma unroll
        for (int i = 0; i < 16; ++i) {
            atomicAdd(&s_sum[cg * 16 + i], sum[i]);
            atomicAdd(&s_sq[cg * 16 + i], sq[i]);
        }
    }
    __syncthreads();
    if (threadIdx.x < 64) {
        atomicAdd(&stats[threadIdx.x], (double)s_sum[threadIdx.x]);
        atomicAdd(&stats[64 + threadIdx.x], (double)s_sq[threadIdx.x]);
    }
}

// ----------------------------------------------------- w_final -> bf16
__global__ __launch_bounds__(256) void wconv_kernel(const float* __restrict__ w,
                                                    __hip_bfloat16* __restrict__ wb) {
    int t = blockIdx.x * 256 + threadIdx.x;   // 1024*512
    wb[t] = __float2bfloat16(w[t]);
}

// -------------------- graph max-pool + input-BN+LReLU + 1x1 conv + stats
// XCD-swizzled block decode: batch = blockIdx & 15 (all 32 blocks of a batch
// share one XCD with round-robin mapping -> neighbor slab stays L2-resident).
template <int CIN, int COUT, int PT>
__global__ __launch_bounds__(256) void layer_kernel(float* __restrict__ cat,
                                                    const int* __restrict__ idx,
                                                    const float* __restrict__ w,
                                                    const float* __restrict__ bias,
                                                    const double* __restrict__ stats_in,
                                                    double invcnt_in,
                                                    double* __restrict__ stats_out,
                                                    int off_in, int off_out) {
    constexpr int P = 64;
    constexpr int LDC = CIN + 4;        // g row stride, 16B-aligned
    constexpr int WS = COUT + 4;        // wt row stride
    constexpr int NCG = CIN / 4;        // channel float4 groups
    constexpr int PPAR = 256 / NCG;     // points gathered in parallel
    constexpr int NOG = COUT / 4;       // output quad groups
    static_assert(NOG * (P / PT) == 256, "thread mapping");

    __shared__ float g[P * LDC];
    __shared__ float wt[16 * WS];       // [cc][o] — lane-contiguous, conflict-free
    __shared__ float s_sum[COUT], s_sq[COUT];

    const int b = blockIdx.x & 15;      // XCD swizzle: batch fast-varying
    const int pb = blockIdx.x >> 4;     // 0..31
    const int pt0 = b * N_ + pb * P;    // flattened b*N+n

    // ---- gather + max + input BN/LReLU
    {
        const int cg = threadIdx.x % NCG;
        const int pp = threadIdx.x / NCG;
        float mean[4], inv[4];
#pragma unroll
        for (int j = 0; j < 4; ++j) {
            const double mu = stats_in[cg * 4 + j] * invcnt_in;
            const double e2 = stats_in[CIN + cg * 4 + j] * invcnt_in;
            const float var = (float)(e2 - mu * mu);
            mean[j] = (float)mu;
            inv[j] = rsqrtf(var + EPS_);
        }
        for (int p = pp; p < P; p += PPAR) {
            const int* ip = idx + (size_t)(pt0 + p) * KNN;
            float4 m = make_float4(-INFINITY, -INFINITY, -INFINITY, -INFINITY);
#pragma unroll
            for (int k = 0; k < KNN; ++k) {
                const int j = ip[k];
                const float4 v = *(const float4*)&cat[(size_t)(b * N_ + j) * 512 + off_in + cg * 4];
                m.x = fmaxf(m.x, v.x); m.y = fmaxf(m.y, v.y);
                m.z = fmaxf(m.z, v.z); m.w = fmaxf(m.w, v.w);
            }
            float4 r;
            r.x = (m.x - mean[0]) * inv[0]; r.x = r.x >= 0.f ? r.x : SLOPE * r.x;
            r.y = (m.y - mean[1]) * inv[1]; r.y = r.y >= 0.f ? r.y : SLOPE * r.y;
            r.z = (m.z - mean[2]) * inv[2]; r.z = r.z >= 0.f ? r.z : SLOPE * r.z;
            r.w = (m.w - mean[3]) * inv[3]; r.w = r.w >= 0.f ? r.w : SLOPE * r.w;
            *(float4*)&g[p * LDC + cg * 4] = r;
        }
    }
    if (threadIdx.x < COUT) { s_sum[threadIdx.x] = 0.f; s_sq[threadIdx.x] = 0.f; }

    // ---- conv: 4 outs x PT points per thread
    const int og = threadIdx.x % NOG;
    const int pg = threadIdx.x / NOG;
    const int o0 = og * 4, p0 = pg * PT;

    float acc[4][PT];
#pragma unroll
    for (int i = 0; i < 4; ++i)
#pragma unroll
        for (int j = 0; j < PT; ++j) acc[i][j] = 0.f;

    for (int c0 = 0; c0 < CIN; c0 += 16) {
        __syncthreads();
        for (int i = threadIdx.x; i < COUT * 16; i += 256) {
            int o = i >> 4, cc = i & 15;
            wt[cc * WS + o] = w[(size_t)o * CIN + c0 + cc];
        }
        __syncthreads();
#pragma unroll
        for (int ccq = 0; ccq < 4; ++ccq) {
            const float4 w0 = *(const float4*)&wt[(ccq * 4 + 0) * WS + o0];
            const float4 w1 = *(const float4*)&wt[(ccq * 4 + 1) * WS + o0];
            const float4 w2 = *(const float4*)&wt[(ccq * 4 + 2) * WS + o0];
            const float4 w3 = *(const float4*)&wt[(ccq * 4 + 3) * WS + o0];
#pragma unroll
            for (int p = 0; p < PT; ++p) {
                const float4 gv = *(const float4*)&g[(p0 + p) * LDC + c0 + ccq * 4];
                acc[0][p] += w0.x * gv.x; acc[0][p] += w1.x * gv.y;
                acc[0][p] += w2.x * gv.z; acc[0][p] += w3.x * gv.w;
                acc[1][p] += w0.y * gv.x; acc[1][p] += w1.y * gv.y;
                acc[1][p] += w2.y * gv.z; acc[1][p] += w3.y * gv.w;
                acc[2][p] += w0.z * gv.x; acc[2][p] += w1.z * gv.y;
                acc[2][p] += w2.z * gv.z; acc[2][p] += w3.z * gv.w;
                acc[3][p] += w0.w * gv.x; acc[3][p] += w1.w * gv.y;
                acc[3][p] += w2.w * gv.z; acc[3][p] += w3.w * gv.w;
            }
        }
    }

    // ---- epilogue: bias, stats, contiguous float4 stores (PRE-BN output)
    const float4 bv = *(const float4*)&bias[o0];
    float lsum[4] = {0.f, 0.f, 0.f, 0.f}, lsq[4] = {0.f, 0.f, 0.f, 0.f};
#pragma unroll
    for (int p = 0; p < PT; ++p) {
        float4 hv;
        hv.x = acc[0][p] + bv.x; hv.y = acc[1][p] + bv.y;
        hv.z = acc[2][p] + bv.z; hv.w = acc[3][p] + bv.w;
        lsum[0] += hv.x; lsq[0] += hv.x * hv.x;
        lsum[1] += hv.y; lsq[1] += hv.y * hv.y;
        lsum[2] += hv.z; lsq[2] += hv.z * hv.z;
        lsum[3] += hv.w; lsq[3] += hv.w * hv.w;
        *(float4*)&cat[(size_t)(pt0 + p0 + p) * 512 + off_out + o0] = hv;
    }
#pragma unroll
    for (int i = 0; i < 4; ++i) {
        atomicAdd(&s_sum[o0 + i], lsum[i]);
        atomicAdd(&s_sq[o0 + i], lsq[i]);
    }
    __syncthreads();
    if (threadIdx.x < COUT) {
        atomicAdd(&stats_out[threadIdx.x], (double)s_sum[threadIdx.x]);
        atomicAdd(&stats_out[COUT + threadIdx.x], (double)s_sq[threadIdx.x]);
    }
}

// ------------- fused BN+LReLU -> bf16 for all 512 channels (final GEMM input)
__global__ __launch_bounds__(256) void bnconv_kernel(const float* __restrict__ cat,
                                                     const double* __restrict__ stats,
                                                     unsigned short* __restrict__ catb,
                                                     double ik, double in_) {
    const int t = blockIdx.x * 256 + threadIdx.x;   // over 32768*128 float4s
    const int pn = t >> 7;
    const int c = (t & 127) * 4;

    const double* sp; const double* qp; double icnt;
    if (c < 64)       { sp = stats + c;             qp = stats + 64 + c;        icnt = ik; }
    else if (c < 128) { sp = stats + 128 + (c - 64);  qp = stats + 192 + (c - 64);  icnt = in_; }
    else if (c < 256) { sp = stats + 256 + (c - 128); qp = stats + 384 + (c - 128); icnt = in_; }
    else              { sp = stats + 512 + (c - 256); qp = stats + 768 + (c - 256); icnt = in_; }

    const float4 v = *(const float4*)&cat[(size_t)pn * 512 + c];
    float r[4]; const float vv[4] = {v.x, v.y, v.z, v.w};
#pragma unroll
    for (int j = 0; j < 4; ++j) {
        const double mu = sp[j] * icnt;
        const double e2 = qp[j] * icnt;
        const float var = (float)(e2 - mu * mu);
        const float inv = rsqrtf(var + EPS_);
        float x = (vv[j] - (float)mu) * inv;
        r[j] = x >= 0.f ? x : SLOPE * x;
    }
    ushort4 o;
    __hip_bfloat16 h0 = __float2bfloat16(r[0]); o.x = *(unsigned short*)&h0;
    __hip_bfloat16 h1 = __float2bfloat16(r[1]); o.y = *(unsigned short*)&h1;
    __hip_bfloat16 h2 = __float2bfloat16(r[2]); o.z = *(unsigned short*)&h2;
    __hip_bfloat16 h3 = __float2bfloat16(r[3]); o.w = *(unsigned short*)&h3;
    *(ushort4*)&catb[(size_t)pn * 512 + c] = o;
}

// -------------- final GEMM via bf16 MFMA + bias + max-over-n (register staging)
// 1D grid 2048, XCD-aware decode: plo = bid&7 binds pblk (mod 8) to one XCD;
// the 8 ob-blocks sharing an A tile are bids {plo + 8*ob + 64*phi} -> same
// XCD, near-consecutive -> A tile (131 KB) L2-hot across its 8 uses; B
// (1 MB) L2-resident. Cuts LLC/HBM staging ~268 MB -> ~35 MB.
__global__ __launch_bounds__(256) void final_mfma_kernel(const short* __restrict__ catb,
                                                         const short* __restrict__ wb,
                                                         const float* __restrict__ bias,
                                                         float* __restrict__ partial) {
    constexpr int LDK = 72;              // 64 + 8 pad: 144 B row stride (16B-aligned)
    __shared__ short As[128 * LDK];
    __shared__ short Bs[128 * LDK];
    __shared__ float red[256];

    const int bid = blockIdx.x;
    const int plo = bid & 7;
    const int ob = (bid >> 3) & 7;
    const int pblk = ((bid >> 6) << 3) | plo;   // 0..255
    const int pt0 = pblk * 128;

    const int wid = threadIdx.x >> 6;
    const int lane = threadIdx.x & 63;
    const int wm = wid >> 1, wn = wid & 1;   // 2x2 wave grid -> 64x64 per wave
    const int lm = lane & 15, g = lane >> 4;

    const int srow = threadIdx.x >> 1;
    const int scg = (threadIdx.x & 1) * 32;
    const short* ga = catb + (size_t)(pt0 + srow) * 512 + scg;
    const short* gb = wb + (size_t)(ob * 128 + srow) * 512 + scg;
    short* la = As + srow * LDK + scg;
    short* lb = Bs + srow * LDK + scg;

    float4v acc[4][4];
#pragma unroll
    for (int i = 0; i < 4; ++i)
#pragma unroll
        for (int j = 0; j < 4; ++j) acc[i][j] = {0.f, 0.f, 0.f, 0.f};

    short8 ra[4], rb[4];
#pragma unroll
    for (int j = 0; j < 4; ++j) {
        ra[j] = *(const short8*)(ga + j * 8);
        rb[j] = *(const short8*)(gb + j * 8);
    }

    for (int step = 0; step < 8; ++step) {
        __syncthreads();
#pragma unroll
        for (int j = 0; j < 4; ++j) {
            *(short8*)(la + j * 8) = ra[j];
            *(short8*)(lb + j * 8) = rb[j];
        }
        __syncthreads();
        if (step < 7) {
            const int c1 = (step + 1) * 64;
#pragma unroll
            for (int j = 0; j < 4; ++j) {
                ra[j] = *(const short8*)(ga + c1 + j * 8);
                rb[j] = *(const short8*)(gb + c1 + j * 8);
            }
        }
#pragma unroll
        for (int kk = 0; kk < 2; ++kk) {
            short8 a[4], b[4];
#pragma unroll
            for (int t = 0; t < 4; ++t) {
                a[t] = *(const short8*)&As[(wm * 64 + t * 16 + lm) * LDK + kk * 32 + g * 8];
                b[t] = *(const short8*)&Bs[(wn * 64 + t * 16 + lm) * LDK + kk * 32 + g * 8];
            }
#pragma unroll
            for (int mt = 0; mt < 4; ++mt)
#pragma unroll
                for (int nt = 0; nt < 4; ++nt)
                    acc[mt][nt] = __builtin_amdgcn_mfma_f32_16x16x32_bf16(
                        a[mt], b[nt], acc[mt][nt], 0, 0, 0);
        }
    }

    float cm[4];
#pragma unroll
    for (int nt = 0; nt < 4; ++nt) {
        float m = -INFINITY;
#pragma unroll
        for (int mt = 0; mt < 4; ++mt)
#pragma unroll
            for (int r = 0; r < 4; ++r) m = fmaxf(m, acc[mt][nt][r]);
        m = fmaxf(m, __shfl_xor(m, 16, 64));
        m = fmaxf(m, __shfl_xor(m, 32, 64));
        cm[nt] = m;
    }
    __syncthreads();
    if (lane < 16) {
#pragma unroll
        for (int nt = 0; nt < 4; ++nt)
            red[wm * 128 + wn * 64 + nt * 16 + lane] = cm[nt];
    }
    __syncthreads();
    if (threadIdx.x < 128) {
        const int o = threadIdx.x;
        float v = fmaxf(red[o], red[128 + o]) + bias[ob * 128 + o];
        partial[(size_t)pblk * 1024 + ob * 128 + o] = v;
    }
}

// ----------------------------------------------------------- final reduce
__global__ __launch_bounds__(256) void reduce_kernel(const float* __restrict__ partial,
                                                     float* __restrict__ out) {
    int t = blockIdx.x * 256 + threadIdx.x;   // 16384
    int b = t >> 10, o = t & 1023;
    float m = -INFINITY;
#pragma unroll 4
    for (int i = 0; i < 16; ++i)
        m = fmaxf(m, partial[(size_t)((b * 16 + i) * 1024) + o]);
    out[t] = m;
}

// ---------------------------------------------------------------- launch
extern "C" void kernel_launch(void* const* d_in, const int* in_sizes, int n_in,
                              void* d_out, int out_size, void* d_ws, size_t ws_size,
                              hipStream_t stream) {
    const float* x = (const float*)d_in[0];
    const float* w_edge = (const float*)d_in[1];
    const float* b_edge = (const float*)d_in[2];
    const float* w1 = (const float*)d_in[3];
    const float* b1 = (const float*)d_in[4];
    const float* w2 = (const float*)d_in[5];
    const float* b2 = (const float*)d_in[6];
    const float* w3 = (const float*)d_in[7];
    const float* b3 = (const float*)d_in[8];
    const float* w_final = (const float*)d_in[9];
    const float* b_final = (const float*)d_in[10];
    float* out = (float*)d_out;

    char* ws = (char*)d_ws;
    int* idx = (int*)ws;                                     // 2,621,440 B
    float* cat = (float*)(ws + 2621440);                     // 67,108,864 B  (PRE-BN)
    float* partial = (float*)(ws + 69730304);                // 1,048,576 B
    double* stats = (double*)(ws + 70778880);                // 8,192 B
    __hip_bfloat16* catb = (__hip_bfloat16*)(ws + 70787072); // 33,554,432 B  (post-BN bf16)
    __hip_bfloat16* wb = (__hip_bfloat16*)(ws + 104341504);  // 1,048,576 B

    double* st_e = stats;
    double* st_1 = stats + 128;
    double* st_2 = stats + 256;
    double* st_3 = stats + 512;
    const double ik = 1.0 / ((double)B_ * N_ * KNN);
    const double in_ = 1.0 / ((double)B_ * N_);

    hipMemsetAsync(stats, 0, 1024 * sizeof(double), stream);
    wconv_kernel<<<2048, 256, 0, stream>>>(w_final, wb);

    knn_kernel<<<B_ * 32, 256, 0, stream>>>(x, idx, w_edge, b_edge, cat, st_e);
    layer_kernel<64, 64, 4><<<(B_ * N_) / 64, 256, 0, stream>>>(
        cat, idx, w1, b1, st_e, ik, st_1, 0, 64);
    layer_kernel<64, 128, 8><<<(B_ * N_) / 64, 256, 0, stream>>>(
        cat, idx, w2, b2, st_1, in_, st_2, 64, 128);
    layer_kernel<128, 256, 16><<<(B_ * N_) / 64, 256, 0, stream>>>(
        cat, idx, w3, b3, st_2, in_, st_3, 128, 256);
    bnconv_kernel<<<(B_ * N_ * 128) / 256, 256, 0, stream>>>(
        cat, stats, (unsigned short*)catb, ik, in_);
    final_mfma_kernel<<<2048, 256, 0, stream>>>((const short*)catb, (const short*)wb,
                                                b_final, partial);
    reduce_kernel<<<64, 256, 0, stream>>>(partial, out);
}